// Round 3
// 323.484 us; speedup vs baseline: 1.0840x; 1.0840x over previous
//
#include <hip/hip_runtime.h>
#include <math.h>

// HydraChannelMixer, MI355X (gfx950). Round 5: de-risked operand-swap.
// vs proven 345us baseline, ONLY these deltas (no workspace growth, no asm):
// - down-proj & up-proj MFMAs operand-swapped (W^T @ h^T): same packed weight
//   tiles reused as A-operands (A/B lane maps are transposes); C-layout puts
//   d (resp. r) on the reg axis -> phase-6 epilogue = 8 float4 stores +
//   8 u16x4 residual reads per thread (was 32 scalar stores + 32 scalar LDS
//   reads, wave-imbalanced), phase-2 fixup fully vectorized
// - dn1/dn2 inner loops use split accumulators (shorter serial FMA chain)
// Workspace layout/preproc identical to the proven baseline (107,776 B).
// Shapes: B=64, C=21, P=96, D=256, R=32, H=64. One block per bp-row.

#define DD 256
#define CC 21
#define RR 32
#define HH 64
#define PP 96
#define BB 64
#define PD (PP * DD)
#define NBP (BB * PP)     // 6144
#define NT 256

#define HBS 264           // hbf row stride (shorts): 528B, multiple of 16B
#define LWS 40            // lowbf row stride (shorts): 80B, multiple of 16B

// d_ws layout (bytes) — identical to proven baseline
#define WS_WDB  0         // 8192 sh: Wd' bf16 frags, 16 tiles (kb*2+ni)*512
#define WS_W4B  16384     // 4096 sh: [Wq|Wk|Wv|Wg] bf16 frags, 8 tiles
#define WS_WUB  24576     // 8192 sh: Wu bf16 frags, 16 tiles
#define WS_DN1P 40960     // 16384 sh: dn1w^T packed bf16 [kb][j][8]
#define WS_DN2P 73728     // 16384 sh: dn2w packed bf16 [jb][d][8]
#define WS_S1   106496    // 32 f32: sum_k bf16(ln_w*Wd)[k][r]
#define WS_S2   106624    // 32 f32: ln_b@Wd + bd
#define WS_LG   106752    // 256 f32: channel_logits

typedef __attribute__((ext_vector_type(8))) short bf16x8;
typedef __attribute__((ext_vector_type(4))) float f32x4;
typedef __attribute__((ext_vector_type(4))) unsigned short u16x4;

__device__ __forceinline__ float gelu_exact(float x) {
    return 0.5f * x * (1.0f + erff(x * 0.70710678118654752440f));
}
__device__ __forceinline__ float sigmoidf_(float x) {
    return 1.0f / (1.0f + __expf(-x));
}
__device__ __forceinline__ short f2bf(float f) {            // RNE f32->bf16
    union { float f; unsigned u; } v; v.f = f;
    unsigned r = v.u + 0x7FFFu + ((v.u >> 16) & 1u);
    return (short)(unsigned short)(r >> 16);
}
__device__ __forceinline__ float bf2f_s(short s) {
    union { unsigned u; float f; } v; v.u = ((unsigned)(unsigned short)s) << 16;
    return v.f;
}

// DPP butterfly add: runs on VALU pipe (not LDS), ~2cyc issue each.
#define DPP_ADD(v, ctrl)                                                      \
    (v) += __builtin_bit_cast(float, __builtin_amdgcn_update_dpp(             \
               0, __builtin_bit_cast(int, (v)), (ctrl), 0xF, 0xF, true))

// all-lane sum over each contiguous 16-lane row: xor1, xor2, ror4, ror8
__device__ __forceinline__ float rowsum16(float v) {
    DPP_ADD(v, 0xB1);   // quad_perm(1,0,3,2) = xor1
    DPP_ADD(v, 0x4E);   // quad_perm(2,3,0,1) = xor2
    DPP_ADD(v, 0x124);  // row_ror:4
    DPP_ADD(v, 0x128);  // row_ror:8
    return v;
}
__device__ __forceinline__ float rdlane(float v, int l) {
    return __builtin_bit_cast(float,
        __builtin_amdgcn_readlane(__builtin_bit_cast(int, v), l));
}

// ---------------------------------------------------------------------------
// Preprocess (27 blocks) — IDENTICAL to proven baseline.
// MFMA frag layout (16x16x32): lane l holds elem[k=(l>>4)*8+j][idx16=l&15];
// this serves as A-frag (idx16=m) or B-frag (idx16=n) interchangeably.
// ---------------------------------------------------------------------------
extern "C" __global__ __launch_bounds__(NT)
void hydra_preproc(const float* __restrict__ ln_w, const float* __restrict__ ln_b,
                   const float* __restrict__ Wd,   const float* __restrict__ bd,
                   const float* __restrict__ Wq,   const float* __restrict__ Wk,
                   const float* __restrict__ Wv,   const float* __restrict__ Wg,
                   const float* __restrict__ Wu,
                   const float* __restrict__ cn1w, const float* __restrict__ cn1b,
                   const float* __restrict__ cn2w, const float* __restrict__ cn2b,
                   const float* __restrict__ dn1w, const float* __restrict__ dn2w,
                   short* __restrict__ WdB, short* __restrict__ W4B,
                   short* __restrict__ WuB, short* __restrict__ dn1P,
                   short* __restrict__ dn2P,
                   float* __restrict__ s1p, float* __restrict__ s2p,
                   float* __restrict__ logits)
{
    const int t = threadIdx.x, lane = t & 63, w = t >> 6, bid = blockIdx.x;
    const int q = lane >> 4, nl = lane & 15;

    if (bid < 4) {                       // WdB: 16 tiles, tile = kb*2 + ni
        int tile = bid * 4 + w;
        int kb = tile >> 1, ni = tile & 1;
        int kbase = kb * 32 + q * 8;
        int n = ni * 16 + nl;
        bf16x8 o;
        #pragma unroll
        for (int j = 0; j < 8; ++j) {
            int k = kbase + j;
            o[j] = f2bf(ln_w[k] * Wd[k * RR + n]);
        }
        *(bf16x8*)(WdB + tile * 512 + lane * 8) = o;
    } else if (bid < 6) {                // W4B: 8 tiles
        int ni = (bid - 4) * 4 + w;
        int n = ni * 16 + nl;
        const float* Wsel = (n < 32) ? Wq : (n < 64) ? Wk : (n < 96) ? Wv : Wg;
        int nn = n & 31;
        bf16x8 o;
        #pragma unroll
        for (int j = 0; j < 8; ++j) o[j] = f2bf(Wsel[(q * 8 + j) * RR + nn]);
        *(bf16x8*)(W4B + ni * 512 + lane * 8) = o;
    } else if (bid < 10) {               // WuB: 16 tiles
        int ni = (bid - 6) * 4 + w;
        int n = ni * 16 + nl;
        bf16x8 o;
        #pragma unroll
        for (int j = 0; j < 8; ++j) o[j] = f2bf(Wu[(q * 8 + j) * DD + n]);
        *(bf16x8*)(WuB + ni * 512 + lane * 8) = o;
    } else if (bid == 10) {              // s1, s2, channel logits
        __shared__ float red1[8][33], red2[8][33];
        __shared__ float clh[HH];
        int r = t & 31, ks = t >> 5;
        float a1 = 0.f, a2 = 0.f;
        for (int k = ks * 32; k < ks * 32 + 32; ++k) {
            float wv = Wd[k * RR + r];
            a1 += bf2f_s(f2bf(ln_w[k] * wv));   // match MFMA's bf16-rounded tile
            a2 += ln_b[k] * wv;
        }
        red1[ks][r] = a1; red2[ks][r] = a2;
        if (t < HH) {
            const float lc = 0.44073977f;       // log(21)/log(1000)
            clh[t] = gelu_exact(lc * cn1w[t] + cn1b[t]);
        }
        __syncthreads();
        if (t < RR) {
            float s1 = 0.f, s2 = 0.f;
            #pragma unroll
            for (int s = 0; s < 8; ++s) { s1 += red1[s][t]; s2 += red2[s][t]; }
            s1p[t] = s1;
            s2p[t] = s2 + bd[t];
        }
        float a = 0.f;
        #pragma unroll 8
        for (int j = 0; j < HH; ++j) a += clh[j] * cn2w[j * DD + t];
        logits[t] = a + cn2b[t];
    } else if (bid < 19) {               // dn1P: [kb][j][8], kb=0..31, j=0..63
        int slot = (bid - 11) * 256 + t; // 0..2047
        int kb = slot >> 6, j = slot & 63;
        bf16x8 o;
        #pragma unroll
        for (int ki = 0; ki < 8; ++ki) o[ki] = f2bf(dn1w[(kb * 8 + ki) * HH + j]);
        *(bf16x8*)(dn1P + slot * 8) = o;
    } else {                             // dn2P: [jb][d][8], jb=0..7, d=0..255
        int slot = (bid - 19) * 256 + t;
        int jb = slot >> 8, d = slot & 255;
        bf16x8 o;
        #pragma unroll
        for (int ji = 0; ji < 8; ++ji) o[ji] = f2bf(dn2w[(jb * 8 + ji) * DD + d]);
        *(bf16x8*)(dn2P + slot * 8) = o;
    }
}

// ---------------------------------------------------------------------------
// Main fused kernel: one block per bp-row, 256 threads (4 waves), 5 barriers.
// ---------------------------------------------------------------------------
extern "C" __global__ __launch_bounds__(NT, 5)
void hydra_fused(const float* __restrict__ x,
                 const float* __restrict__ bg,   const float* __restrict__ bu,
                 const float* __restrict__ dn1b, const float* __restrict__ dn2b,
                 const float* __restrict__ eps_p,
                 const short* __restrict__ WdB,  const short* __restrict__ W4B,
                 const short* __restrict__ WuB,  const short* __restrict__ dn1P,
                 const short* __restrict__ dn2P,
                 const float* __restrict__ s1p,  const float* __restrict__ s2p,
                 const float* __restrict__ logits,
                 float* __restrict__ out)
{
    __shared__ __align__(16) short  hbf[CC * HBS];    // 11,088 B  bf16 h tile
    __shared__ __align__(16) short  lowbf[32 * LWS];  //  2,560 B  [c][r] h_low -> M
    __shared__ __align__(16) float  sh_cv[DD];        //  1,024 B
    __shared__ __align__(16) float2 murs[32];         //    256 B  (mu, rs)
    __shared__ __align__(16) float  dn1p[128];        //    512 B  dn1 partials
    __shared__ __align__(16) float  sh_h1[HH];        //    256 B
    __shared__ __align__(16) float  gfp[64];          //    256 B  gf partials
    __shared__ __align__(16) float  sh_gf[RR];        //    128 B
    __shared__ __align__(16) float  sh_gate[DD];      //  1,024 B

    const int t    = threadIdx.x;
    const int lane = t & 63;
    const int w    = t >> 6;
    const int quad = lane >> 4;
    const int nl   = lane & 15;
    const int bp = blockIdx.x;
    const int b  = bp / PP;
    const int p  = bp - b * PP;
    const float* xbase = x   + (size_t)b * CC * PD + (size_t)p * DD;
    float*       obase = out + (size_t)b * CC * PD + (size_t)p * DD;

    // ---- Phase 1: load h tile (wave w owns row iter*4+w), bf16 to LDS,
    //      LN stats per row via DPP butterflies (f32 precision from regs) ----
    #pragma unroll
    for (int iter = 0; iter < 6; ++iter) {
        int c = iter * 4 + w;
        bool act = (c < CC);
        float4 v = make_float4(0.f, 0.f, 0.f, 0.f);
        if (act) v = *(const float4*)(xbase + (size_t)c * PD + lane * 4);
        if (act) {
            u16x4 u;
            u[0] = (unsigned short)f2bf(v.x); u[1] = (unsigned short)f2bf(v.y);
            u[2] = (unsigned short)f2bf(v.z); u[3] = (unsigned short)f2bf(v.w);
            *(u16x4*)(hbf + c * HBS + lane * 4) = u;
        }
        float s  = v.x + v.y + v.z + v.w;
        float s2 = v.x * v.x + v.y * v.y + v.z * v.z + v.w * v.w;
        s  = rowsum16(s);
        s2 = rowsum16(s2);
        float tot  = rdlane(s, 0)  + rdlane(s, 16)  + rdlane(s, 32)  + rdlane(s, 48);
        float tot2 = rdlane(s2, 0) + rdlane(s2, 16) + rdlane(s2, 32) + rdlane(s2, 48);
        if (act && lane == 0) {
            float mu  = tot * (1.0f / DD);
            float var = tot2 * (1.0f / DD) - mu * mu;    // biased (LN)
            murs[c] = make_float2(mu, rsqrtf(var + 1e-5f));
        }
    }
    __syncthreads();   // B1

    // ---- Phase 2: channel variance (unbiased over C) + down-proj MFMA,
    //      operand-swapped: C[r][c] = (Wd')^T @ h^T, stored to lowbf[c][r] ---
    {
        float cs = 0.f, cs2 = 0.f;
        #pragma unroll
        for (int c = 0; c < CC; ++c) {
            float v = bf2f_s(hbf[c * HBS + t]);
            cs += v; cs2 = fmaf(v, v, cs2);
        }
        sh_cv[t] = (cs2 - cs * cs * (1.0f / CC)) * (1.0f / (CC - 1));
    }
    {   // wave w: r-tile mt = w&1, c-tile ct = w>>1
        const int mt = w & 1, ct = w >> 1;
        const int c  = ct * 16 + nl;
        const int c_rd = (c < CC) ? c : (CC - 1);    // cols>=21: clone ch 20
        const int r0 = mt * 16 + quad * 4;
        f32x4 acc = {0.f, 0.f, 0.f, 0.f};
        #pragma unroll
        for (int kb = 0; kb < 8; ++kb) {
            bf16x8 bh = *(const bf16x8*)(hbf + c_rd * HBS + kb * 32 + quad * 8);
            bf16x8 aw = *(const bf16x8*)(WdB + (kb * 2 + mt) * 512 + lane * 8);
            acc = __builtin_amdgcn_mfma_f32_16x16x32_bf16(aw, bh, acc, 0, 0, 0);
        }
        const float2 mr = murs[c_rd];
        const f32x4 s1v = *(const f32x4*)(s1p + r0);
        const f32x4 s2v = *(const f32x4*)(s2p + r0);
        u16x4 o;
        #pragma unroll
        for (int reg = 0; reg < 4; ++reg)
            o[reg] = (unsigned short)f2bf(
                mr.y * (acc[reg] - mr.x * s1v[reg]) + s2v[reg]);
        *(u16x4*)(lowbf + c * LWS + r0) = o;
    }
    __syncthreads();   // B2

    // ---- Phase 3: waves 0,2: QKVG MFMA + norms + content gate + KV pool;
    //               waves 1,3: dn1 (packed bf16, coalesced b128) -------------
    const int mi2 = w >> 1;
    float qg0[4], qg1[4];
    if ((w & 1) == 0) {
        const int m = mi2 * 16 + nl;
        bf16x8 a = *(const bf16x8*)(lowbf + m * LWS + quad * 8);
        f32x4 acc[8];
        #pragma unroll
        for (int i = 0; i < 8; ++i) {
            bf16x8 bw = *(const bf16x8*)(W4B + i * 512 + lane * 8);
            f32x4 z = {0.f, 0.f, 0.f, 0.f};
            acc[i] = __builtin_amdgcn_mfma_f32_16x16x32_bf16(a, bw, z, 0, 0, 0);
        }
        // tiles: 0,1=Q | 2,3=K | 4,5=V | 6,7=G ; lane cols nl and 16+nl
        const float bg0 = bg[nl], bg1 = bg[16 + nl];
        float kv0 = 0.f, kv1 = 0.f;
        #pragma unroll
        for (int reg = 0; reg < 4; ++reg) {
            float q0 = acc[0][reg], q1 = acc[1][reg];
            float k0 = acc[2][reg], k1 = acc[3][reg];
            float q2 = rowsum16(q0 * q0 + q1 * q1);      // sum over 32 cols
            float k2 = rowsum16(k0 * k0 + k1 * k1);
            float qi = 1.0f / fmaxf(sqrtf(q2), 1e-12f);
            float ki = 1.0f / fmaxf(sqrtf(k2), 1e-12f);
            float g0 = sigmoidf_(acc[6][reg] + bg0);
            float g1 = sigmoidf_(acc[7][reg] + bg1);
            qg0[reg] = q0 * qi * g0;
            qg1[reg] = q1 * qi * g1;
            int rowg = mi2 * 16 + quad * 4 + reg;
            float msk = (rowg < CC) ? 1.0f : 0.0f;
            kv0 += msk * (k0 * ki * acc[4][reg]);
            kv1 += msk * (k1 * ki * acc[5][reg]);
        }
        kv0 += __shfl_xor(kv0, 16); kv0 += __shfl_xor(kv0, 32);
        kv1 += __shfl_xor(kv1, 16); kv1 += __shfl_xor(kv1, 32);
        if (quad == 0) {
            gfp[mi2 * 32 + nl]      = kv0;
            gfp[mi2 * 32 + 16 + nl] = kv1;
        }
    } else {
        const int half = w >> 1;     // waves 1,3 split K over two halves
        float p0 = 0.f, p1 = 0.f;
        #pragma unroll
        for (int i = 0; i < 16; ++i) {
            int kb = half * 16 + i;
            bf16x8 wv = *(const bf16x8*)(dn1P + (kb * 64 + lane) * 8);
            f32x4 c0 = *(const f32x4*)(sh_cv + kb * 8);
            f32x4 c1 = *(const f32x4*)(sh_cv + kb * 8 + 4);
            p0 += bf2f_s(wv[0]) * c0[0] + bf2f_s(wv[1]) * c0[1]
                + bf2f_s(wv[2]) * c0[2] + bf2f_s(wv[3]) * c0[3];
            p1 += bf2f_s(wv[4]) * c1[0] + bf2f_s(wv[5]) * c1[1]
                + bf2f_s(wv[6]) * c1[2] + bf2f_s(wv[7]) * c1[3];
        }
        dn1p[half * 64 + lane] = p0 + p1;
    }
    __syncthreads();   // B3

    // ---- Phase 4: finalize h1 and global_feat ------------------------------
    if (t < HH) sh_h1[t] = gelu_exact(dn1p[t] + dn1p[64 + t] + dn1b[t]);
    if (t < RR) sh_gf[t] = gfp[t] + gfp[32 + t];
    __syncthreads();   // B4

    // ---- Phase 5: adaptive gate (dn2, packed bf16) + write M ---------------
    {
        const float eps = eps_p[0];
        float a0 = 0.f, a1 = 0.f;
        #pragma unroll
        for (int jb = 0; jb < 8; ++jb) {
            bf16x8 wv = *(const bf16x8*)(dn2P + (jb * 256 + t) * 8);
            f32x4 h0 = *(const f32x4*)(sh_h1 + jb * 8);
            f32x4 h1 = *(const f32x4*)(sh_h1 + jb * 8 + 4);
            a0 += bf2f_s(wv[0]) * h0[0] + bf2f_s(wv[1]) * h0[1]
                + bf2f_s(wv[2]) * h0[2] + bf2f_s(wv[3]) * h0[3];
            a1 += bf2f_s(wv[4]) * h1[0] + bf2f_s(wv[5]) * h1[1]
                + bf2f_s(wv[6]) * h1[2] + bf2f_s(wv[7]) * h1[3];
        }
        sh_gate[t] = sigmoidf_(logits[t] + eps * (a0 + a1 + dn2b[t]));
    }
    if ((w & 1) == 0) {              // M = (Qn*gate_c)*gf, to lowbf[c][r]
        float gf0 = sh_gf[nl], gf1 = sh_gf[16 + nl];
        #pragma unroll
        for (int reg = 0; reg < 4; ++reg) {
            int rowg = mi2 * 16 + quad * 4 + reg;
            lowbf[rowg * LWS + nl]      = f2bf(qg0[reg] * gf0);
            lowbf[rowg * LWS + 16 + nl] = f2bf(qg1[reg] * gf1);
        }
    }
    __syncthreads();   // B5

    // ---- Phase 6: up-proj operand-swapped: C[d][c] = Wu^T @ M^T ------------
    // wave w owns d-tiles w*4..w*4+3, both c-tiles; reg axis = 4 consecutive d
    {
        bf16x8 bf0 = *(const bf16x8*)(lowbf + nl * LWS + quad * 8);        // c=nl
        bf16x8 bf1 = *(const bf16x8*)(lowbf + (16 + nl) * LWS + quad * 8); // c=16+nl
        const int c0 = nl, c1 = 16 + nl;
        #pragma unroll
        for (int i = 0; i < 4; ++i) {
            const int dt = w * 4 + i;
            bf16x8 af = *(const bf16x8*)(WuB + dt * 512 + lane * 8);
            f32x4 z = {0.f, 0.f, 0.f, 0.f};
            f32x4 a0 = __builtin_amdgcn_mfma_f32_16x16x32_bf16(af, bf0, z, 0, 0, 0);
            f32x4 a1 = __builtin_amdgcn_mfma_f32_16x16x32_bf16(af, bf1, z, 0, 0, 0);
            const int db = dt * 16 + quad * 4;
            const f32x4 gd  = *(const f32x4*)(sh_gate + db);
            const f32x4 bud = *(const f32x4*)(bu + db);
            {
                u16x4 h4 = *(const u16x4*)(hbf + c0 * HBS + db);
                f32x4 o;
                #pragma unroll
                for (int reg = 0; reg < 4; ++reg)
                    o[reg] = fmaf(gd[reg], a0[reg] + bud[reg],
                                  bf2f_s((short)h4[reg]));
                *(f32x4*)(obase + (size_t)c0 * PD + db) = o;
            }
            if (nl < CC - 16) {      // c1 < 21
                u16x4 h4 = *(const u16x4*)(hbf + c1 * HBS + db);
                f32x4 o;
                #pragma unroll
                for (int reg = 0; reg < 4; ++reg)
                    o[reg] = fmaf(gd[reg], a1[reg] + bud[reg],
                                  bf2f_s((short)h4[reg]));
                *(f32x4*)(obase + (size_t)c1 * PD + db) = o;
            }
        }
    }
}

extern "C" void kernel_launch(void* const* d_in, const int* in_sizes, int n_in,
                              void* d_out, int out_size, void* d_ws, size_t ws_size,
                              hipStream_t stream) {
    const float* x    = (const float*)d_in[0];
    const float* ln_w = (const float*)d_in[1];
    const float* ln_b = (const float*)d_in[2];
    const float* Wd   = (const float*)d_in[3];
    const float* bd   = (const float*)d_in[4];
    const float* Wq   = (const float*)d_in[5];
    const float* Wk   = (const float*)d_in[6];
    const float* Wv   = (const float*)d_in[7];
    const float* Wg   = (const float*)d_in[8];
    const float* bg   = (const float*)d_in[9];
    const float* Wu   = (const float*)d_in[10];
    const float* bu   = (const float*)d_in[11];
    const float* cn1w = (const float*)d_in[12];
    const float* cn1b = (const float*)d_in[13];
    const float* cn2w = (const float*)d_in[14];
    const float* cn2b = (const float*)d_in[15];
    const float* dn1w = (const float*)d_in[16];
    const float* dn1b = (const float*)d_in[17];
    const float* dn2w = (const float*)d_in[18];
    const float* dn2b = (const float*)d_in[19];
    const float* eps  = (const float*)d_in[20];
    float* out = (float*)d_out;

    char* ws = (char*)d_ws;
    short* WdB  = (short*)(ws + WS_WDB);
    short* W4B  = (short*)(ws + WS_W4B);
    short* WuB  = (short*)(ws + WS_WUB);
    short* dn1P = (short*)(ws + WS_DN1P);
    short* dn2P = (short*)(ws + WS_DN2P);
    float* s1p  = (float*)(ws + WS_S1);
    float* s2p  = (float*)(ws + WS_S2);
    float* lg   = (float*)(ws + WS_LG);

    hydra_preproc<<<27, NT, 0, stream>>>(ln_w, ln_b, Wd, bd, Wq, Wk, Wv, Wg, Wu,
                                         cn1w, cn1b, cn2w, cn2b, dn1w, dn2w,
                                         WdB, W4B, WuB, dn1P, dn2P, s1p, s2p, lg);
    hydra_fused<<<NBP, NT, 0, stream>>>(x, bg, bu, dn1b, dn2b, eps,
                                        WdB, W4B, WuB, dn1P, dn2P, s1p, s2p, lg,
                                        out);
}